// Round 10
// baseline (2300.757 us; speedup 1.0000x reference)
//
#include <hip/hip_runtime.h>

// SimpleRNN: VOCAB=32000, EMBED=256, HIDDEN=512, N=256, L=512
// out = h_512 (256x512 f32), h_{t+1} = tanh(h W_hh^T + b_hh + b_xh + emb[X] W_xh^T)
//
// Round-10: W fully STREAMED from L2 every step (no resident W at all).
//  r8 (resident+stream tail) spilled; r9 (all-resident, 1 wave/SIMD) stalled.
//  Full W = 512KB = the whole per-CU RF -> residency and TLP are mutually
//  exclusive. Stream instead: per CU/step 512KB from L2 (~420 B/cyc/XCD << L2 BW),
//  live set ~110 regs at 2 waves/SIMD, LDS reads halve (h only: 128/step/CU).
//  16 blocks x 512 thr; h dbuf 32KB static LDS; 1 barrier/step (round-6 core).

typedef _Float16 f16;
typedef f16 f16x8 __attribute__((ext_vector_type(8)));
typedef float f32x4 __attribute__((ext_vector_type(4)));
typedef unsigned short u16;

union U8 { uint4 u; f16x8 h; };
union U4 { uint2 u; f16 h[4]; };

// ---------------------------------------------------------------- preconv ---
// One frag = 64 lanes x 8 f16 (1KB). lane l supplies W[col = c16*16 + (l&15)][k = kt*32 + (l>>4)*8 + j].
// mode 0 (W_xh, K=256): f = c16*8 + kt    [round-6 phaseA layout, known-good]
// mode 1 (W_hh, K=512): f = c16*16 + kt   [round-9-passed layout]
__global__ void preconv_kernel(const float* __restrict__ W, u16* __restrict__ dst,
                               int kstride, int mode) {
  int t = blockIdx.x * blockDim.x + threadIdx.x;
  int f = t >> 6, l = t & 63;
  int kt, c16;
  if (mode == 0) { kt = f & 7;  c16 = f >> 3; }
  else           { kt = f & 15; c16 = f >> 4; }
  int col = c16 * 16 + (l & 15);
  int k   = kt * 32 + (l >> 4) * 8;
  const float* src = W + (size_t)col * kstride + k;
  float4 v0 = *(const float4*)src;
  float4 v1 = *(const float4*)(src + 4);
  U8 r;
  r.h = (f16x8){(f16)v0.x, (f16)v0.y, (f16)v0.z, (f16)v0.w,
                (f16)v1.x, (f16)v1.y, (f16)v1.z, (f16)v1.w};
  *(uint4*)(dst + (size_t)f * 512 + l * 8) = r.u;
}

// ----------------------------------------------------------------- phaseA ---
// Round-6 exact (known-good). Grid 1024 = 16 bn x 64 bl. 512 thr, 8 waves.
// Writes xpf[t][cq][n][4] f16, cq = out_col>>2 (0..127), n = batch row, biases folded.
__global__ __launch_bounds__(512, 2) void phaseA_kernel(
    const int* __restrict__ X, const float* __restrict__ emb,
    const u16* __restrict__ Wxf, const float* __restrict__ b_hh,
    const float* __restrict__ b_xh, u16* __restrict__ xpf) {
  __shared__ f16 A[128 * 256];  // 64 KB
  const int tid = threadIdx.x, w = tid >> 6, l = tid & 63;
  const int b = blockIdx.x, bn = b >> 6, bl = b & 63;
  const int lr = l & 15, lg = l >> 4;

  f16x8 wx[4][8];
#pragma unroll
  for (int mt = 0; mt < 4; ++mt)
#pragma unroll
    for (int kt = 0; kt < 8; ++kt) {
      U8 u; u.u = *(const uint4*)(Wxf + (size_t)((w * 4 + mt) * 8 + kt) * 512 + l * 8);
      wx[mt][kt] = u.h;
    }
  float bias[4][4];
#pragma unroll
  for (int mt = 0; mt < 4; ++mt)
#pragma unroll
    for (int r = 0; r < 4; ++r) {
      int c = w * 64 + mt * 16 + lg * 4 + r;
      bias[mt][r] = b_hh[c] + b_xh[c];
    }

  int xs[16];
  const int lseq = bl * 8 + w;
#pragma unroll
  for (int i = 0; i < 16; ++i) xs[i] = X[(bn * 16 + i) * 512 + lseq];
#pragma unroll
  for (int i = 0; i < 16; ++i) {
    float4 v = *(const float4*)(emb + (size_t)xs[i] * 256 + l * 4);
    U4 p; p.h[0] = (f16)v.x; p.h[1] = (f16)v.y; p.h[2] = (f16)v.z; p.h[3] = (f16)v.w;
    int row = w * 16 + i;
    *(uint2*)(&A[row * 256 + ((l * 4) ^ ((row & 7) << 3))]) = p.u;
  }
  __syncthreads();

#pragma unroll 1
  for (int nt = 0; nt < 8; ++nt) {
    f32x4 acc[4];
#pragma unroll
    for (int mt = 0; mt < 4; ++mt) acc[mt] = (f32x4){0.f, 0.f, 0.f, 0.f};
    const f16* Brow = &A[(nt * 16 + lr) * 256];
    const int sw = (lr & 7) << 3;
#pragma unroll
    for (int kt = 0; kt < 8; ++kt) {
      f16x8 bfr = *(const f16x8*)(Brow + ((kt * 32 + lg * 8) ^ sw));
#pragma unroll
      for (int mt = 0; mt < 4; ++mt)
        acc[mt] = __builtin_amdgcn_mfma_f32_16x16x32_f16(wx[mt][kt], bfr, acc[mt], 0, 0, 0);
    }
    const int t = bl * 8 + nt;
#pragma unroll
    for (int mt = 0; mt < 4; ++mt) {
      U4 p;
#pragma unroll
      for (int r = 0; r < 4; ++r) p.h[r] = (f16)(acc[mt][r] + bias[mt][r]);
      *(uint2*)(xpf + (size_t)t * 131072 + (w * 16 + mt * 4 + lg) * 1024
                    + (bn * 16 + lr) * 4) = p.u;
    }
  }
}

// ----------------------------------------------------------------- phaseB ---
// 16 blocks x 512 thr (8 waves, 2/SIMD). Block bb: batch rows [16bb,16bb+16).
// Wave w: out cols [64w,64w+64) (c16 = w*4+mt, mt=0..3). W streamed from L2:
// frag (mt,kt) at Whf + (w*64 + mt*16 + kt)*512 + l*8, ping-pong 1 kt ahead.
// h[16][512] f16 dbuf in static LDS; storage: row*512 + (col ^ ((row&7)<<3)).

#define HFRAG(HR, KT) (*(const f16x8*)((HR) + lr * 512 + (((KT) * 32 + lg * 8) ^ asw)))

#define WLOAD(DST, KT)                                                            \
  do { _Pragma("unroll")                                                          \
    for (int mt = 0; mt < 4; ++mt)                                                \
      DST[mt].u = *(const uint4*)(wb + (size_t)(mt * 16 + (KT)) * 512);           \
  } while (0)

#define KT_BODY(HR, KT, WF)                                                       \
  do { f16x8 hf = HFRAG(HR, KT);                                                  \
    _Pragma("unroll")                                                             \
    for (int mt = 0; mt < 4; ++mt)                                                \
      acc[mt] = __builtin_amdgcn_mfma_f32_16x16x32_f16(WF[mt].h, hf, acc[mt], 0, 0, 0); \
  } while (0)

#define STEP(T, HR, HW, XPc, XPn)                                                 \
  do {                                                                            \
    { /* prefetch xp for step T+1 (clamped, in-bounds) */                         \
      const int tn = ((T) + 1 < 512) ? ((T) + 1) : 511;                           \
      const u16* p = xpb + (size_t)tn * 131072;                                   \
      _Pragma("unroll")                                                           \
      for (int mt = 0; mt < 4; ++mt) XPn[mt] = *(const uint2*)(p + mt * 4096);    \
    }                                                                             \
    U8 wf0[4], wf1[4];                                                            \
    WLOAD(wf0, 0);                                                                \
    f32x4 acc[4];                                                                 \
    _Pragma("unroll")  /* init acc from xp (saves zero-init + epilogue add) */    \
    for (int mt = 0; mt < 4; ++mt) {                                              \
      U4 px; px.u = XPc[mt];                                                      \
      acc[mt] = (f32x4){(float)px.h[0], (float)px.h[1],                           \
                        (float)px.h[2], (float)px.h[3]};                          \
    }                                                                             \
    WLOAD(wf1, 1);  KT_BODY(HR, 0, wf0);                                          \
    WLOAD(wf0, 2);  KT_BODY(HR, 1, wf1);                                          \
    WLOAD(wf1, 3);  KT_BODY(HR, 2, wf0);                                          \
    WLOAD(wf0, 4);  KT_BODY(HR, 3, wf1);                                          \
    WLOAD(wf1, 5);  KT_BODY(HR, 4, wf0);                                          \
    WLOAD(wf0, 6);  KT_BODY(HR, 5, wf1);                                          \
    WLOAD(wf1, 7);  KT_BODY(HR, 6, wf0);                                          \
    WLOAD(wf0, 8);  KT_BODY(HR, 7, wf1);                                          \
    WLOAD(wf1, 9);  KT_BODY(HR, 8, wf0);                                          \
    WLOAD(wf0, 10); KT_BODY(HR, 9, wf1);                                          \
    WLOAD(wf1, 11); KT_BODY(HR, 10, wf0);                                         \
    WLOAD(wf0, 12); KT_BODY(HR, 11, wf1);                                         \
    WLOAD(wf1, 13); KT_BODY(HR, 12, wf0);                                         \
    WLOAD(wf0, 14); KT_BODY(HR, 13, wf1);                                         \
    WLOAD(wf1, 15); KT_BODY(HR, 14, wf0);                                         \
    KT_BODY(HR, 15, wf1);                                                         \
    _Pragma("unroll")                                                             \
    for (int mt = 0; mt < 4; ++mt) {                                              \
      U4 o;                                                                       \
      _Pragma("unroll")                                                           \
      for (int r = 0; r < 4; ++r) {                                               \
        float z = acc[mt][r];                                                     \
        float e = __builtin_amdgcn_exp2f(z * 2.885390081777927f);                 \
        o.h[r] = (f16)(1.0f - 2.0f * __builtin_amdgcn_rcpf(e + 1.0f));            \
      }                                                                           \
      *(uint2*)((HW) + lr * 512 + ((w * 64 + mt * 16 + lg * 4) ^ asw)) = o.u;     \
    }                                                                             \
    __syncthreads();                                                              \
  } while (0)

__global__ __launch_bounds__(512)
__attribute__((amdgpu_waves_per_eu(2, 2)))
void phaseB_kernel(const u16* __restrict__ Whf, const u16* __restrict__ xpf,
                   float* __restrict__ out) {
  __shared__ f16 hb0[16 * 512];  // 16 KB (even steps read)
  __shared__ f16 hb1[16 * 512];  // 16 KB
  const int tid = threadIdx.x, w = tid >> 6, l = tid & 63;
  const int bb = blockIdx.x;
  const int lr = l & 15, lg = l >> 4;
  const int asw = (lr & 7) << 3;

  { // h0 = 0 (hb1 fully written before first read)
    float* hz = (float*)hb0;
#pragma unroll
    for (int i = 0; i < 8; ++i) hz[i * 512 + tid] = 0.f;
  }
  __syncthreads();

  // invariants: per-wave W base (64KB contiguous chunk), xp base
  const u16* wb  = Whf + (size_t)(w * 64) * 512 + l * 8;
  const u16* xpb = xpf + (size_t)(w * 16 + lg) * 1024 + (bb * 16 + lr) * 4;

  uint2 xpA[4], xpB[4];
#pragma unroll
  for (int mt = 0; mt < 4; ++mt) xpA[mt] = *(const uint2*)(xpb + mt * 4096);

#pragma unroll 1
  for (int t2 = 0; t2 < 256; ++t2) {
    const int t = t2 * 2;
    STEP(t,     hb0, hb1, xpA, xpB);   // even: read hb0, write hb1
    STEP(t + 1, hb1, hb0, xpB, xpA);   // odd : read hb1, write hb0
  }

  // final h in hb0 (step 511 wrote it; STEP ends with barrier)
#pragma unroll
  for (int i = 0; i < 16; ++i) {
    f16 v = hb0[i * 512 + (tid ^ ((i & 7) << 3))];
    out[(size_t)(bb * 16 + i) * 512 + tid] = (float)v;
  }
}

#undef STEP
#undef KT_BODY
#undef WLOAD
#undef HFRAG

// ------------------------------------------------------------------ launch --
extern "C" void kernel_launch(void* const* d_in, const int* in_sizes, int n_in,
                              void* d_out, int out_size, void* d_ws, size_t ws_size,
                              hipStream_t stream) {
  const int*   X    = (const int*)d_in[0];
  const float* emb  = (const float*)d_in[1];
  const float* W_hh = (const float*)d_in[2];
  const float* b_hh = (const float*)d_in[3];
  const float* W_xh = (const float*)d_in[4];
  const float* b_xh = (const float*)d_in[5];
  float* out = (float*)d_out;

  char* ws = (char*)d_ws;
  u16* Whf = (u16*)ws;                    // 512 KB
  u16* Wxf = (u16*)(ws + 524288);         // 256 KB
  u16* xpf = (u16*)(ws + 786432);         // 128 MB

  preconv_kernel<<<128, 256, 0, stream>>>(W_hh, Whf, 512, 1);
  preconv_kernel<<< 64, 256, 0, stream>>>(W_xh, Wxf, 256, 0);
  phaseA_kernel<<<1024, 512, 0, stream>>>(X, emb, Wxf, b_hh, b_xh, xpf);
  phaseB_kernel<<<16, 512, 0, stream>>>(Whf, xpf, out);
}

// Round 11
// 2255.653 us; speedup vs baseline: 1.0200x; 1.0200x over previous
//
#include <hip/hip_runtime.h>

// SimpleRNN: VOCAB=32000, EMBED=256, HIDDEN=512, N=256, L=512
// out = h_512 (256x512 f32), h_{t+1} = tanh(h W_hh^T + b_hh + b_xh + emb[X] W_xh^T)
//
// Round-11: FULL W_hh residency per wave (64 frags = 256 regs) using the
// unified RF correctly: 56 frags -> AGPR (MFMA A-operands), 8 frags -> VGPR.
// At 2 waves/SIMD budget is 256 VGPR + 256 AGPR per wave; round 6 used only 320.
// Zero W LDS traffic -> LDS = h-dbuf only (128 b128 reads/CU/step ~2300 cyc
// < MFMA floor 2484 cyc) -> MFMA-bound. r8/r10 streaming + r9 1-wave/SIMD all
// falsified by counters (spill WRITE_SIZE / latency).

typedef _Float16 f16;
typedef f16 f16x8 __attribute__((ext_vector_type(8)));
typedef float f32x4 __attribute__((ext_vector_type(4)));
typedef unsigned short u16;

union U8 { uint4 u; f16x8 h; };
union U4 { uint2 u; f16 h[4]; };

// ---------------------------------------------------------------- preconv ---
// One frag = 64 lanes x 8 f16 (1KB). lane l supplies W[col = c16*16 + (l&15)][k = kt*32 + (l>>4)*8 + j].
// mode 0 (W_xh, K=256): f = c16*8 + kt    [round-6 phaseA layout, known-good]
// mode 1 (W_hh, K=512): f = kt*32 + c16   [uniform, no tail section]
__global__ void preconv_kernel(const float* __restrict__ W, u16* __restrict__ dst,
                               int kstride, int mode) {
  int t = blockIdx.x * blockDim.x + threadIdx.x;
  int f = t >> 6, l = t & 63;
  int kt, c16;
  if (mode == 0) { kt = f & 7;  c16 = f >> 3; }
  else           { kt = f >> 5; c16 = f & 31; }
  int col = c16 * 16 + (l & 15);
  int k   = kt * 32 + (l >> 4) * 8;
  const float* src = W + (size_t)col * kstride + k;
  float4 v0 = *(const float4*)src;
  float4 v1 = *(const float4*)(src + 4);
  U8 r;
  r.h = (f16x8){(f16)v0.x, (f16)v0.y, (f16)v0.z, (f16)v0.w,
                (f16)v1.x, (f16)v1.y, (f16)v1.z, (f16)v1.w};
  *(uint4*)(dst + (size_t)f * 512 + l * 8) = r.u;
}

// ----------------------------------------------------------------- phaseA ---
// Round-6 exact (known-good). Grid 1024 = 16 bn x 64 bl. 512 thr, 8 waves.
// Writes xpf[t][cq][n][4] f16, cq = out_col>>2 (0..127), n = batch row, biases folded.
__global__ __launch_bounds__(512, 2) void phaseA_kernel(
    const int* __restrict__ X, const float* __restrict__ emb,
    const u16* __restrict__ Wxf, const float* __restrict__ b_hh,
    const float* __restrict__ b_xh, u16* __restrict__ xpf) {
  __shared__ f16 A[128 * 256];  // 64 KB
  const int tid = threadIdx.x, w = tid >> 6, l = tid & 63;
  const int b = blockIdx.x, bn = b >> 6, bl = b & 63;
  const int lr = l & 15, lg = l >> 4;

  f16x8 wx[4][8];
#pragma unroll
  for (int mt = 0; mt < 4; ++mt)
#pragma unroll
    for (int kt = 0; kt < 8; ++kt) {
      U8 u; u.u = *(const uint4*)(Wxf + (size_t)((w * 4 + mt) * 8 + kt) * 512 + l * 8);
      wx[mt][kt] = u.h;
    }
  float bias[4][4];
#pragma unroll
  for (int mt = 0; mt < 4; ++mt)
#pragma unroll
    for (int r = 0; r < 4; ++r) {
      int c = w * 64 + mt * 16 + lg * 4 + r;
      bias[mt][r] = b_hh[c] + b_xh[c];
    }

  int xs[16];
  const int lseq = bl * 8 + w;
#pragma unroll
  for (int i = 0; i < 16; ++i) xs[i] = X[(bn * 16 + i) * 512 + lseq];
#pragma unroll
  for (int i = 0; i < 16; ++i) {
    float4 v = *(const float4*)(emb + (size_t)xs[i] * 256 + l * 4);
    U4 p; p.h[0] = (f16)v.x; p.h[1] = (f16)v.y; p.h[2] = (f16)v.z; p.h[3] = (f16)v.w;
    int row = w * 16 + i;
    *(uint2*)(&A[row * 256 + ((l * 4) ^ ((row & 7) << 3))]) = p.u;
  }
  __syncthreads();

#pragma unroll 1
  for (int nt = 0; nt < 8; ++nt) {
    f32x4 acc[4];
#pragma unroll
    for (int mt = 0; mt < 4; ++mt) acc[mt] = (f32x4){0.f, 0.f, 0.f, 0.f};
    const f16* Brow = &A[(nt * 16 + lr) * 256];
    const int sw = (lr & 7) << 3;
#pragma unroll
    for (int kt = 0; kt < 8; ++kt) {
      f16x8 bfr = *(const f16x8*)(Brow + ((kt * 32 + lg * 8) ^ sw));
#pragma unroll
      for (int mt = 0; mt < 4; ++mt)
        acc[mt] = __builtin_amdgcn_mfma_f32_16x16x32_f16(wx[mt][kt], bfr, acc[mt], 0, 0, 0);
    }
    const int t = bl * 8 + nt;
#pragma unroll
    for (int mt = 0; mt < 4; ++mt) {
      U4 p;
#pragma unroll
      for (int r = 0; r < 4; ++r) p.h[r] = (f16)(acc[mt][r] + bias[mt][r]);
      *(uint2*)(xpf + (size_t)t * 131072 + (w * 16 + mt * 4 + lg) * 1024
                    + (bn * 16 + lr) * 4) = p.u;
    }
  }
}

// ----------------------------------------------------------------- phaseB ---
// 16 blocks x 512 thr (8 waves, 2/SIMD). Block bb: batch rows [16bb,16bb+16).
// Wave w: out cols [64w,64w+64) (c16 = w*4+mt). Full W resident:
//   wa[14][4] (224 regs, expect AGPR) + wv[2][4] (32 regs, expect VGPR).
// h[16][512] f16 dbuf in static LDS; storage: row*512 + (col ^ ((row&7)<<3)).

#define HFRAG(HR, KT) (*(const f16x8*)((HR) + lr * 512 + (((KT) * 32 + lg * 8) ^ asw)))

#define KT_A(HR, KT)                                                              \
  do { f16x8 hf = HFRAG(HR, KT);                                                  \
    _Pragma("unroll")                                                             \
    for (int mt = 0; mt < 4; ++mt)                                                \
      acc[mt] = __builtin_amdgcn_mfma_f32_16x16x32_f16(wa[KT][mt], hf, acc[mt], 0, 0, 0); \
  } while (0)

#define KT_V(HR, KT)                                                              \
  do { f16x8 hf = HFRAG(HR, KT);                                                  \
    _Pragma("unroll")                                                             \
    for (int mt = 0; mt < 4; ++mt)                                                \
      acc[mt] = __builtin_amdgcn_mfma_f32_16x16x32_f16(wv[(KT) - 14][mt], hf, acc[mt], 0, 0, 0); \
  } while (0)

#define STEP(T, HR, HW, XPc, XPn)                                                 \
  do {                                                                            \
    { /* prefetch xp for step T+1 (clamped, in-bounds) */                         \
      const int tn = ((T) + 1 < 512) ? ((T) + 1) : 511;                           \
      const u16* p = xpb + (size_t)tn * 131072;                                   \
      _Pragma("unroll")                                                           \
      for (int mt = 0; mt < 4; ++mt) XPn[mt] = *(const uint2*)(p + mt * 4096);    \
    }                                                                             \
    f32x4 acc[4];                                                                 \
    _Pragma("unroll")  /* init acc from xp (saves zero-init + epilogue add) */    \
    for (int mt = 0; mt < 4; ++mt) {                                              \
      U4 px; px.u = XPc[mt];                                                      \
      acc[mt] = (f32x4){(float)px.h[0], (float)px.h[1],                           \
                        (float)px.h[2], (float)px.h[3]};                          \
    }                                                                             \
    KT_A(HR, 0);  KT_A(HR, 1);  KT_A(HR, 2);  KT_A(HR, 3);                        \
    KT_A(HR, 4);  KT_A(HR, 5);  KT_A(HR, 6);  KT_A(HR, 7);                        \
    KT_A(HR, 8);  KT_A(HR, 9);  KT_A(HR, 10); KT_A(HR, 11);                       \
    KT_A(HR, 12); KT_A(HR, 13); KT_V(HR, 14); KT_V(HR, 15);                       \
    _Pragma("unroll")                                                             \
    for (int mt = 0; mt < 4; ++mt) {                                              \
      U4 o;                                                                       \
      _Pragma("unroll")                                                           \
      for (int r = 0; r < 4; ++r) {                                               \
        float z = acc[mt][r];                                                     \
        float e = __builtin_amdgcn_exp2f(z * 2.885390081777927f);                 \
        o.h[r] = (f16)(1.0f - 2.0f * __builtin_amdgcn_rcpf(e + 1.0f));            \
      }                                                                           \
      *(uint2*)((HW) + lr * 512 + ((w * 64 + mt * 16 + lg * 4) ^ asw)) = o.u;     \
    }                                                                             \
    __syncthreads();                                                              \
  } while (0)

__global__ __launch_bounds__(512)
__attribute__((amdgpu_waves_per_eu(2, 2)))
void phaseB_kernel(const u16* __restrict__ Whf, const u16* __restrict__ xpf,
                   float* __restrict__ out) {
  __shared__ f16 hb0[16 * 512];  // 16 KB (even steps read)
  __shared__ f16 hb1[16 * 512];  // 16 KB
  const int tid = threadIdx.x, w = tid >> 6, l = tid & 63;
  const int bb = blockIdx.x;
  const int lr = l & 15, lg = l >> 4;
  const int asw = (lr & 7) << 3;

  // Full W resident: frag (kt,mt) at f = kt*32 + w*4 + mt.
  f16x8 wa[14][4];  // kt 0..13 -> expect AGPR (224 regs)
  f16x8 wv[2][4];   // kt 14,15 -> expect VGPR (32 regs)
#pragma unroll
  for (int kt = 0; kt < 14; ++kt)
#pragma unroll
    for (int mt = 0; mt < 4; ++mt) {
      U8 u; u.u = *(const uint4*)(Whf + (size_t)(kt * 32 + w * 4 + mt) * 512 + l * 8);
      wa[kt][mt] = u.h;
    }
#pragma unroll
  for (int kt = 0; kt < 2; ++kt)
#pragma unroll
    for (int mt = 0; mt < 4; ++mt) {
      U8 u; u.u = *(const uint4*)(Whf + (size_t)((kt + 14) * 32 + w * 4 + mt) * 512 + l * 8);
      wv[kt][mt] = u.h;
    }

  { // h0 = 0 (hb1 fully written before first read)
    float* hz = (float*)hb0;
#pragma unroll
    for (int i = 0; i < 8; ++i) hz[i * 512 + tid] = 0.f;
  }
  __syncthreads();

  // xp base: xpf[t][cq= w*16+mt*4+lg][n= bb*16+lr][4]
  const u16* xpb = xpf + (size_t)(w * 16 + lg) * 1024 + (bb * 16 + lr) * 4;

  uint2 xpA[4], xpB[4];
#pragma unroll
  for (int mt = 0; mt < 4; ++mt) xpA[mt] = *(const uint2*)(xpb + mt * 4096);

#pragma unroll 1
  for (int t2 = 0; t2 < 256; ++t2) {
    const int t = t2 * 2;
    STEP(t,     hb0, hb1, xpA, xpB);   // even: read hb0, write hb1
    STEP(t + 1, hb1, hb0, xpB, xpA);   // odd : read hb1, write hb0
  }

  // final h in hb0 (step 511 wrote it; STEP ends with barrier)
#pragma unroll
  for (int i = 0; i < 16; ++i) {
    f16 v = hb0[i * 512 + (tid ^ ((i & 7) << 3))];
    out[(size_t)(bb * 16 + i) * 512 + tid] = (float)v;
  }
}

#undef STEP
#undef KT_V
#undef KT_A
#undef HFRAG

// ------------------------------------------------------------------ launch --
extern "C" void kernel_launch(void* const* d_in, const int* in_sizes, int n_in,
                              void* d_out, int out_size, void* d_ws, size_t ws_size,
                              hipStream_t stream) {
  const int*   X    = (const int*)d_in[0];
  const float* emb  = (const float*)d_in[1];
  const float* W_hh = (const float*)d_in[2];
  const float* b_hh = (const float*)d_in[3];
  const float* W_xh = (const float*)d_in[4];
  const float* b_xh = (const float*)d_in[5];
  float* out = (float*)d_out;

  char* ws = (char*)d_ws;
  u16* Whf = (u16*)ws;                    // 512 KB
  u16* Wxf = (u16*)(ws + 524288);         // 256 KB
  u16* xpf = (u16*)(ws + 786432);         // 128 MB

  preconv_kernel<<<128, 256, 0, stream>>>(W_hh, Whf, 512, 1);
  preconv_kernel<<< 64, 256, 0, stream>>>(W_xh, Wxf, 256, 0);
  phaseA_kernel<<<1024, 512, 0, stream>>>(X, emb, Wxf, b_hh, b_xh, xpf);
  phaseB_kernel<<<16, 512, 0, stream>>>(Whf, xpf, out);
}

// Round 12
// 2233.078 us; speedup vs baseline: 1.0303x; 1.0101x over previous
//
#include <hip/hip_runtime.h>

// SimpleRNN: VOCAB=32000, EMBED=256, HIDDEN=512, N=256, L=512
// out = h_512 (256x512 f32), h_{t+1} = tanh(h W_hh^T + b_hh + b_xh + emb[X] W_xh^T)
//
// Round-12: r10's all-streamed-W structure + THE REGISTER-BUDGET FIX.
//  Diagnosis: VGPR_Count=128 in r6/r8/r10/r11 -> amdgpu_waves_per_eu never took
//  effect; the allocator ran at a 128-reg cap, causing every spill (WRITE_SIZE
//  10MB) and silent W reload. r9's __launch_bounds__(256,1) -> VGPR 240 proves
//  the 2nd launch_bounds arg is the lever. Here: __launch_bounds__(512,2)
//  (8 waves/block, 1 block/CU -> 2 waves/SIMD, 256 regs/wave).
//  W fully streamed from L2, 4-buffer lookahead (~230cyc >= L2 latency);
//  LDS = h dbuf only (32KB static, ~2100cyc/step < MFMA floor 2484) -> MFMA-bound.

typedef _Float16 f16;
typedef f16 f16x8 __attribute__((ext_vector_type(8)));
typedef float f32x4 __attribute__((ext_vector_type(4)));
typedef unsigned short u16;

union U8 { uint4 u; f16x8 h; };
union U4 { uint2 u; f16 h[4]; };

// ---------------------------------------------------------------- preconv ---
// One frag = 64 lanes x 8 f16 (1KB). lane l supplies W[col = c16*16 + (l&15)][k = kt*32 + (l>>4)*8 + j].
// mode 0 (W_xh, K=256): f = c16*8 + kt    [round-6 phaseA layout, known-good]
// mode 1 (W_hh, K=512): f = c16*16 + kt   [round-10-passed layout]
__global__ void preconv_kernel(const float* __restrict__ W, u16* __restrict__ dst,
                               int kstride, int mode) {
  int t = blockIdx.x * blockDim.x + threadIdx.x;
  int f = t >> 6, l = t & 63;
  int kt, c16;
  if (mode == 0) { kt = f & 7;  c16 = f >> 3; }
  else           { kt = f & 15; c16 = f >> 4; }
  int col = c16 * 16 + (l & 15);
  int k   = kt * 32 + (l >> 4) * 8;
  const float* src = W + (size_t)col * kstride + k;
  float4 v0 = *(const float4*)src;
  float4 v1 = *(const float4*)(src + 4);
  U8 r;
  r.h = (f16x8){(f16)v0.x, (f16)v0.y, (f16)v0.z, (f16)v0.w,
                (f16)v1.x, (f16)v1.y, (f16)v1.z, (f16)v1.w};
  *(uint4*)(dst + (size_t)f * 512 + l * 8) = r.u;
}

// ----------------------------------------------------------------- phaseA ---
// Round-6 exact (known-good). Grid 1024 = 16 bn x 64 bl. 512 thr, 8 waves.
// Writes xpf[t][cq][n][4] f16, cq = out_col>>2 (0..127), n = batch row, biases folded.
__global__ __launch_bounds__(512, 2) void phaseA_kernel(
    const int* __restrict__ X, const float* __restrict__ emb,
    const u16* __restrict__ Wxf, const float* __restrict__ b_hh,
    const float* __restrict__ b_xh, u16* __restrict__ xpf) {
  __shared__ f16 A[128 * 256];  // 64 KB
  const int tid = threadIdx.x, w = tid >> 6, l = tid & 63;
  const int b = blockIdx.x, bn = b >> 6, bl = b & 63;
  const int lr = l & 15, lg = l >> 4;

  f16x8 wx[4][8];
#pragma unroll
  for (int mt = 0; mt < 4; ++mt)
#pragma unroll
    for (int kt = 0; kt < 8; ++kt) {
      U8 u; u.u = *(const uint4*)(Wxf + (size_t)((w * 4 + mt) * 8 + kt) * 512 + l * 8);
      wx[mt][kt] = u.h;
    }
  float bias[4][4];
#pragma unroll
  for (int mt = 0; mt < 4; ++mt)
#pragma unroll
    for (int r = 0; r < 4; ++r) {
      int c = w * 64 + mt * 16 + lg * 4 + r;
      bias[mt][r] = b_hh[c] + b_xh[c];
    }

  int xs[16];
  const int lseq = bl * 8 + w;
#pragma unroll
  for (int i = 0; i < 16; ++i) xs[i] = X[(bn * 16 + i) * 512 + lseq];
#pragma unroll
  for (int i = 0; i < 16; ++i) {
    float4 v = *(const float4*)(emb + (size_t)xs[i] * 256 + l * 4);
    U4 p; p.h[0] = (f16)v.x; p.h[1] = (f16)v.y; p.h[2] = (f16)v.z; p.h[3] = (f16)v.w;
    int row = w * 16 + i;
    *(uint2*)(&A[row * 256 + ((l * 4) ^ ((row & 7) << 3))]) = p.u;
  }
  __syncthreads();

#pragma unroll 1
  for (int nt = 0; nt < 8; ++nt) {
    f32x4 acc[4];
#pragma unroll
    for (int mt = 0; mt < 4; ++mt) acc[mt] = (f32x4){0.f, 0.f, 0.f, 0.f};
    const f16* Brow = &A[(nt * 16 + lr) * 256];
    const int sw = (lr & 7) << 3;
#pragma unroll
    for (int kt = 0; kt < 8; ++kt) {
      f16x8 bfr = *(const f16x8*)(Brow + ((kt * 32 + lg * 8) ^ sw));
#pragma unroll
      for (int mt = 0; mt < 4; ++mt)
        acc[mt] = __builtin_amdgcn_mfma_f32_16x16x32_f16(wx[mt][kt], bfr, acc[mt], 0, 0, 0);
    }
    const int t = bl * 8 + nt;
#pragma unroll
    for (int mt = 0; mt < 4; ++mt) {
      U4 p;
#pragma unroll
      for (int r = 0; r < 4; ++r) p.h[r] = (f16)(acc[mt][r] + bias[mt][r]);
      *(uint2*)(xpf + (size_t)t * 131072 + (w * 16 + mt * 4 + lg) * 1024
                    + (bn * 16 + lr) * 4) = p.u;
    }
  }
}

// ----------------------------------------------------------------- phaseB ---
// 16 blocks x 512 thr (8 waves -> 2/SIMD, 256 regs/wave via launch_bounds(512,2)).
// Block bb: batch rows [16bb,16bb+16). Wave w: out cols [64w,64w+64) (c16=w*4+mt).
// W streamed from L2: frag (mt,kt) at Whf + (w*64 + mt*16 + kt)*512 + l*8,
// 4-buffer rotation, loads issued 4 kt ahead (~230 cyc coverage >= L2 latency).
// h[16][512] f16 dbuf in static LDS; storage: row*512 + (col ^ ((row&7)<<3)).

#define HFRAG(HR, KT) (*(const f16x8*)((HR) + lr * 512 + (((KT) * 32 + lg * 8) ^ asw)))

#define WLOAD(DST, KT)                                                            \
  do { _Pragma("unroll")                                                          \
    for (int mt = 0; mt < 4; ++mt)                                                \
      DST[mt].u = *(const uint4*)(wb + (size_t)(mt * 16 + (KT)) * 512);           \
  } while (0)

#define KT_BODY(HR, KT, WF)                                                       \
  do { f16x8 hf = HFRAG(HR, KT);                                                  \
    _Pragma("unroll")                                                             \
    for (int mt = 0; mt < 4; ++mt)                                                \
      acc[mt] = __builtin_amdgcn_mfma_f32_16x16x32_f16(WF[mt].h, hf, acc[mt], 0, 0, 0); \
  } while (0)

#define STEP(T, HR, HW, XPc, XPn)                                                 \
  do {                                                                            \
    { /* prefetch xp for step T+1 (clamped, in-bounds) */                         \
      const int tn = ((T) + 1 < 512) ? ((T) + 1) : 511;                           \
      const u16* p = xpb + (size_t)tn * 131072;                                   \
      _Pragma("unroll")                                                           \
      for (int mt = 0; mt < 4; ++mt) XPn[mt] = *(const uint2*)(p + mt * 4096);    \
    }                                                                             \
    U8 wfA[4], wfB[4], wfC[4], wfD[4];                                            \
    WLOAD(wfA, 0); WLOAD(wfB, 1); WLOAD(wfC, 2); WLOAD(wfD, 3);                   \
    f32x4 acc[4];                                                                 \
    _Pragma("unroll")  /* init acc from xp (saves zero-init + epilogue add) */    \
    for (int mt = 0; mt < 4; ++mt) {                                              \
      U4 px; px.u = XPc[mt];                                                      \
      acc[mt] = (f32x4){(float)px.h[0], (float)px.h[1],                           \
                        (float)px.h[2], (float)px.h[3]};                          \
    }                                                                             \
    KT_BODY(HR, 0, wfA);  WLOAD(wfA, 4);                                          \
    KT_BODY(HR, 1, wfB);  WLOAD(wfB, 5);                                          \
    KT_BODY(HR, 2, wfC);  WLOAD(wfC, 6);                                          \
    KT_BODY(HR, 3, wfD);  WLOAD(wfD, 7);                                          \
    KT_BODY(HR, 4, wfA);  WLOAD(wfA, 8);                                          \
    KT_BODY(HR, 5, wfB);  WLOAD(wfB, 9);                                          \
    KT_BODY(HR, 6, wfC);  WLOAD(wfC, 10);                                         \
    KT_BODY(HR, 7, wfD);  WLOAD(wfD, 11);                                         \
    KT_BODY(HR, 8, wfA);  WLOAD(wfA, 12);                                         \
    KT_BODY(HR, 9, wfB);  WLOAD(wfB, 13);                                         \
    KT_BODY(HR, 10, wfC); WLOAD(wfC, 14);                                         \
    KT_BODY(HR, 11, wfD); WLOAD(wfD, 15);                                         \
    KT_BODY(HR, 12, wfA); KT_BODY(HR, 13, wfB);                                   \
    KT_BODY(HR, 14, wfC); KT_BODY(HR, 15, wfD);                                   \
    _Pragma("unroll")                                                             \
    for (int mt = 0; mt < 4; ++mt) {                                              \
      U4 o;                                                                       \
      _Pragma("unroll")                                                           \
      for (int r = 0; r < 4; ++r) {                                               \
        float z = acc[mt][r];                                                     \
        float e = __builtin_amdgcn_exp2f(z * 2.885390081777927f);                 \
        o.h[r] = (f16)(1.0f - 2.0f * __builtin_amdgcn_rcpf(e + 1.0f));            \
      }                                                                           \
      *(uint2*)((HW) + lr * 512 + ((w * 64 + mt * 16 + lg * 4) ^ asw)) = o.u;     \
    }                                                                             \
    __syncthreads();                                                              \
  } while (0)

__global__ __launch_bounds__(512, 2)
void phaseB_kernel(const u16* __restrict__ Whf, const u16* __restrict__ xpf,
                   float* __restrict__ out) {
  __shared__ f16 hb0[16 * 512];  // 16 KB (even steps read)
  __shared__ f16 hb1[16 * 512];  // 16 KB
  const int tid = threadIdx.x, w = tid >> 6, l = tid & 63;
  const int bb = blockIdx.x;
  const int lr = l & 15, lg = l >> 4;
  const int asw = (lr & 7) << 3;

  { // h0 = 0 (hb1 fully written before first read)
    float* hz = (float*)hb0;
#pragma unroll
    for (int i = 0; i < 8; ++i) hz[i * 512 + tid] = 0.f;
  }
  __syncthreads();

  // invariants: per-wave W base (64KB contiguous chunk), xp base
  const u16* wb  = Whf + (size_t)(w * 64) * 512 + l * 8;
  const u16* xpb = xpf + (size_t)(w * 16 + lg) * 1024 + (bb * 16 + lr) * 4;

  uint2 xpA[4], xpB[4];
#pragma unroll
  for (int mt = 0; mt < 4; ++mt) xpA[mt] = *(const uint2*)(xpb + mt * 4096);

#pragma unroll 1
  for (int t2 = 0; t2 < 256; ++t2) {
    const int t = t2 * 2;
    STEP(t,     hb0, hb1, xpA, xpB);   // even: read hb0, write hb1
    STEP(t + 1, hb1, hb0, xpB, xpA);   // odd : read hb1, write hb0
  }

  // final h in hb0 (step 511 wrote it; STEP ends with barrier)
#pragma unroll
  for (int i = 0; i < 16; ++i) {
    f16 v = hb0[i * 512 + (tid ^ ((i & 7) << 3))];
    out[(size_t)(bb * 16 + i) * 512 + tid] = (float)v;
  }
}

#undef STEP
#undef KT_BODY
#undef WLOAD
#undef HFRAG

// ------------------------------------------------------------------ launch --
extern "C" void kernel_launch(void* const* d_in, const int* in_sizes, int n_in,
                              void* d_out, int out_size, void* d_ws, size_t ws_size,
                              hipStream_t stream) {
  const int*   X    = (const int*)d_in[0];
  const float* emb  = (const float*)d_in[1];
  const float* W_hh = (const float*)d_in[2];
  const float* b_hh = (const float*)d_in[3];
  const float* W_xh = (const float*)d_in[4];
  const float* b_xh = (const float*)d_in[5];
  float* out = (float*)d_out;

  char* ws = (char*)d_ws;
  u16* Whf = (u16*)ws;                    // 512 KB
  u16* Wxf = (u16*)(ws + 524288);         // 256 KB
  u16* xpf = (u16*)(ws + 786432);         // 128 MB

  preconv_kernel<<<128, 256, 0, stream>>>(W_hh, Whf, 512, 1);
  preconv_kernel<<< 64, 256, 0, stream>>>(W_xh, Wxf, 256, 0);
  phaseA_kernel<<<1024, 512, 0, stream>>>(X, emb, Wxf, b_hh, b_xh, xpf);
  phaseB_kernel<<<16, 512, 0, stream>>>(Whf, xpf, out);
}